// Round 1
// 2540.681 us; speedup vs baseline: 2.3006x; 2.3006x over previous
//
#include <hip/hip_runtime.h>
#include <math.h>

// Problem dims (compile-time)
#define B_SZ 2
#define L_SZ 1024
#define BL (B_SZ * L_SZ)          // 2048 tokens
#define D_MODEL 768
#define N_LAYER 6
#define VOCAB 32000
#define D_INNER 1536
#define D_STATE 16
#define D_CONV 4
#define DT_RANK 48
#define D_EMB 384
#define EPS 1e-5f

// Chunked-scan params: L = NCHUNK * CT
#define NCHUNK 64
#define CT 16
#define XD (DT_RANK + 2 * D_STATE)   // 80, xdbl row stride

typedef float vfloat4 __attribute__((ext_vector_type(4)));
typedef float f32x4  __attribute__((ext_vector_type(4)));
typedef short bf16x8 __attribute__((ext_vector_type(8)));

__device__ __forceinline__ float siluf(float x) {
    return x / (1.f + expf(-x));
}

// ---------------------------------------------------------------------------
// Embedding: hidden[t, 0:384] = emb_w[ids[t]], hidden[t, 384:768] = pos_emb_w[pos[t]]
// Also zeros residual.
// ---------------------------------------------------------------------------
__global__ void embed_kernel(const int* __restrict__ ids, const int* __restrict__ pos,
                             const float* __restrict__ emb, const float* __restrict__ pemb,
                             float* __restrict__ hidden, float* __restrict__ residual) {
    int idx = blockIdx.x * blockDim.x + threadIdx.x;
    if (idx >= BL * D_MODEL) return;
    int c = idx % D_MODEL;
    int t = idx / D_MODEL;
    float v;
    if (c < D_EMB) v = emb[(size_t)ids[t] * D_EMB + c];
    else           v = pemb[(size_t)pos[t] * (D_MODEL - D_EMB) + (c - D_EMB)];
    hidden[idx] = v;
    residual[idx] = 0.f;
}

// ---------------------------------------------------------------------------
// residual += hidden (in-place on residual); out = rmsnorm(residual) * w
// ---------------------------------------------------------------------------
__global__ __launch_bounds__(256) void add_rmsnorm_kernel(
    const float* __restrict__ hidden, float* __restrict__ residual,
    const float* __restrict__ w, float* __restrict__ out) {
    int row = blockIdx.x;
    const float* h = hidden + (size_t)row * D_MODEL;
    float* r = residual + (size_t)row * D_MODEL;
    float* o = out + (size_t)row * D_MODEL;

    float v[3];
    float ss = 0.f;
#pragma unroll
    for (int i = 0; i < 3; i++) {
        int c = threadIdx.x + i * 256;
        float x = h[c] + r[c];
        v[i] = x;
        r[c] = x;
        ss += x * x;
    }
#pragma unroll
    for (int off = 32; off > 0; off >>= 1) ss += __shfl_down(ss, off, 64);
    __shared__ float parts[4];
    __shared__ float s_scale;
    int wid = threadIdx.x >> 6;
    int lane = threadIdx.x & 63;
    if (lane == 0) parts[wid] = ss;
    __syncthreads();
    if (threadIdx.x == 0) {
        float tot = parts[0] + parts[1] + parts[2] + parts[3];
        s_scale = rsqrtf(tot / (float)D_MODEL + EPS);
    }
    __syncthreads();
    float scale = s_scale;
#pragma unroll
    for (int i = 0; i < 3; i++) {
        int c = threadIdx.x + i * 256;
        o[c] = v[i] * scale * w[c];
    }
}

// ---------------------------------------------------------------------------
// Split-bf16 MFMA GEMM: C[M,N] = A[M,K] (row-major, lda) @ B[N,K]^T (+bias, act)
//
// fp32 emulation via 3-term bf16 split: a = ah + al (ah = trunc-to-bf16,
// al = bf16(a - ah)); a*b ~= ah*bh + ah*bl + al*bh. Per-product rel err
// ~2^-15.5, accumulate in fp32 via v_mfma_f32_16x16x32_bf16.
//
// Tile: BM=BN=128, BK=64, 256 threads = 4 waves in 2x2, each wave owns a
// 64x64 quadrant = 4x4 frags of 16x16. LDS is fragment-linear:
//   [region][msub 0..7][ksub 0..1][lane 0..63][8 bf16]
// so every ds_write_b128 / ds_read_b128 is a contiguous 1KB wave access
// (conflict-free by construction; the permutation is pushed onto the global
// load addresses, m173-style).
//
// Assumptions: M % 128 == 0 (BL=2048 ok); K % 8 == 0; if K % 64 != 0 then
// lda > round_up8(K)+56 so A row over-reads stay in-row (dt case: K=48,
// lda=80). B over-reads are guarded (zero-filled).
// ---------------------------------------------------------------------------
#define BMT 128
#define BNT 128
#define BKT 64

__device__ __forceinline__ void cvt8(vfloat4 a, vfloat4 b, bf16x8* hi, bf16x8* lo) {
    bf16x8 h, l;
#pragma unroll
    for (int j = 0; j < 8; j++) {
        float x = (j < 4) ? a[j] : b[j - 4];
        unsigned u = __float_as_uint(x);
        h[j] = (short)(u >> 16);                       // truncated bf16 (hi)
        float r = x - __uint_as_float(u & 0xffff0000u);// exact residual
        l[j] = (short)(__float_as_uint(r) >> 16);      // truncated bf16 (lo)
    }
    *hi = h; *lo = l;
}

__global__ __launch_bounds__(256, 2) void gemm_mfma_kernel(
    const float* __restrict__ A, int lda,
    const float* __restrict__ B,      // [N][K] row-major (B^T layout)
    const float* __restrict__ bias,
    float* __restrict__ C,
    int M, int N, int K, int act) {

    __shared__ __align__(16) short smem[32768];  // 64 KB
    short* Ah = smem;
    short* Al = smem + 8192;
    short* Bh = smem + 16384;
    short* Bl = smem + 24576;

    const int tid  = threadIdx.x;
    const int lane = tid & 63;
    const int wv   = tid >> 6;      // wave 0..3
    const int wm   = wv >> 1;       // 0..1 : row quadrant
    const int wn   = wv & 1;        // 0..1 : col quadrant
    const int bm   = blockIdx.y * BMT;
    const int bn   = blockIdx.x * BNT;

    // staging decomposition: per wave, per i, writes one full subtile (1KB, linear)
    const int r16 = tid & 15;          // row within 16-row subtile
    const int kq  = (tid >> 4) & 3;    // 8-elem k-chunk within 32-k subtile

    f32x4 acc[4][4];
#pragma unroll
    for (int i = 0; i < 4; i++)
#pragma unroll
        for (int j = 0; j < 4; j++)
            acc[i][j] = (f32x4){0.f, 0.f, 0.f, 0.f};

    const vfloat4 zero4 = {0.f, 0.f, 0.f, 0.f};

    for (int k0 = 0; k0 < K; k0 += BKT) {
        // ---- issue global loads (touch no LDS; overlap with tail of prev step)
        vfloat4 fa[4][2], fb[4][2];
#pragma unroll
        for (int i = 0; i < 4; i++) {
            const int msub = (i >> 1) * 4 + wv;
            const int ksub = i & 1;
            const int m  = msub * 16 + r16;
            const int kk = k0 + ksub * 32 + kq * 8;
            {
                const float* p = A + (size_t)(bm + m) * lda + kk;
                fa[i][0] = *(const vfloat4*)p;
                fa[i][1] = *(const vfloat4*)(p + 4);
            }
            {
                const int n = bn + m;
                if (n < N && kk < K) {
                    const float* p = B + (size_t)n * K + kk;
                    fb[i][0] = *(const vfloat4*)p;
                    fb[i][1] = *(const vfloat4*)(p + 4);
                } else {
                    fb[i][0] = zero4; fb[i][1] = zero4;
                }
            }
        }

        __syncthreads();   // prev iteration's readers done

        // ---- convert + fragment-linear LDS write (conflict-free 1KB per wave)
#pragma unroll
        for (int i = 0; i < 4; i++) {
            const int msub = (i >> 1) * 4 + wv;
            const int ksub = i & 1;
            const int soff = ((msub * 2 + ksub) * 64 + lane) * 8;
            bf16x8 h, l;
            cvt8(fa[i][0], fa[i][1], &h, &l);
            *(bf16x8*)(Ah + soff) = h;
            *(bf16x8*)(Al + soff) = l;
            cvt8(fb[i][0], fb[i][1], &h, &l);
            *(bf16x8*)(Bh + soff) = h;
            *(bf16x8*)(Bl + soff) = l;
        }

        __syncthreads();   // tile staged

        // ---- MFMA on the tile
#pragma unroll
        for (int ksub = 0; ksub < 2; ksub++) {
            bf16x8 a_h[4], a_l[4], b_h[4], b_l[4];
#pragma unroll
            for (int mi = 0; mi < 4; mi++) {
                const int off = (((wm * 4 + mi) * 2 + ksub) * 64 + lane) * 8;
                a_h[mi] = *(const bf16x8*)(Ah + off);
                a_l[mi] = *(const bf16x8*)(Al + off);
            }
#pragma unroll
            for (int ni = 0; ni < 4; ni++) {
                const int off = (((wn * 4 + ni) * 2 + ksub) * 64 + lane) * 8;
                b_h[ni] = *(const bf16x8*)(Bh + off);
                b_l[ni] = *(const bf16x8*)(Bl + off);
            }
#pragma unroll
            for (int mi = 0; mi < 4; mi++)
#pragma unroll
                for (int ni = 0; ni < 4; ni++) {
                    acc[mi][ni] = __builtin_amdgcn_mfma_f32_16x16x32_bf16(
                        a_h[mi], b_h[ni], acc[mi][ni], 0, 0, 0);
                    acc[mi][ni] = __builtin_amdgcn_mfma_f32_16x16x32_bf16(
                        a_h[mi], b_l[ni], acc[mi][ni], 0, 0, 0);
                    acc[mi][ni] = __builtin_amdgcn_mfma_f32_16x16x32_bf16(
                        a_l[mi], b_h[ni], acc[mi][ni], 0, 0, 0);
                }
        }
    }

    // ---- epilogue: C/D frag mapping col = lane&15, row = (lane>>4)*4 + r
    const int row0 = bm + wm * 64 + ((lane >> 4) << 2);
    const int col0 = bn + wn * 64 + (lane & 15);
#pragma unroll
    for (int ni = 0; ni < 4; ni++) {
        const int col = col0 + ni * 16;
        if (col < N) {
            const float bv = bias ? bias[col] : 0.f;
#pragma unroll
            for (int mi = 0; mi < 4; mi++) {
#pragma unroll
                for (int r = 0; r < 4; r++) {
                    const int row = row0 + mi * 16 + r;
                    float v = acc[mi][ni][r] + bv;
                    if (act == 1) v = (v > 20.f) ? v : log1pf(expf(v));
                    C[(size_t)row * N + col] = v;
                }
            }
        }
    }
}

// ---------------------------------------------------------------------------
// Depthwise causal conv1d (k=4) + bias + SiLU.
// ---------------------------------------------------------------------------
__global__ void conv_silu_kernel(const float* __restrict__ xz,
                                 const float* __restrict__ cw,
                                 const float* __restrict__ cb,
                                 float* __restrict__ out) {
    int idx = blockIdx.x * blockDim.x + threadIdx.x;
    if (idx >= BL * D_INNER) return;
    int d = idx % D_INNER;
    int t = (idx / D_INNER) % L_SZ;
    int b = idx / (D_INNER * L_SZ);
    const float* xcol = xz + (size_t)b * L_SZ * (2 * D_INNER) + d;
    float s = cb[d];
#pragma unroll
    for (int j = 0; j < D_CONV; j++) {
        int li = t - (D_CONV - 1) + j;
        if (li >= 0) s += xcol[(size_t)li * (2 * D_INNER)] * cw[d * D_CONV + j];
    }
    out[idx] = siluf(s);
}

// ---------------------------------------------------------------------------
// Chunked selective scan, pass A: per-chunk decay product P and zero-seeded
// local final state S, per (b, chunk, d, n).
// ---------------------------------------------------------------------------
__global__ __launch_bounds__(256) void scan_passA_kernel(
    const float* __restrict__ xconv, const float* __restrict__ dt,
    const float* __restrict__ xdbl, const float* __restrict__ A_log,
    float* __restrict__ Pbuf, float* __restrict__ Sbuf) {
    int d = blockIdx.x * 256 + threadIdx.x;
    int c = blockIdx.y;
    int b = blockIdx.z;
    int t0 = c * CT;

    __shared__ float Bsh[CT][D_STATE];
    {
        int row = threadIdx.x >> 4, n = threadIdx.x & 15;   // 256 = CT*D_STATE
        Bsh[row][n] = xdbl[((size_t)(b * L_SZ + t0 + row)) * XD + DT_RANK + n];
    }
    __syncthreads();

    float A[D_STATE];
#pragma unroll
    for (int n = 0; n < D_STATE; n++) A[n] = -expf(A_log[(size_t)d * D_STATE + n]);

    float P[D_STATE], S[D_STATE];
#pragma unroll
    for (int n = 0; n < D_STATE; n++) { P[n] = 1.f; S[n] = 0.f; }

    for (int t = 0; t < CT; t++) {
        size_t row = (size_t)b * L_SZ + t0 + t;
        float dtv = dt[row * D_INNER + d];
        float xv  = xconv[row * D_INNER + d];
#pragma unroll
        for (int n = 0; n < D_STATE; n++) {
            float dA = expf(dtv * A[n]);
            P[n] *= dA;
            S[n] = dA * S[n] + dtv * Bsh[t][n] * xv;
        }
    }
    size_t base = (((size_t)b * NCHUNK + c) * D_INNER + d) * D_STATE;
#pragma unroll
    for (int n = 0; n < D_STATE; n++) { Pbuf[base + n] = P[n]; Sbuf[base + n] = S[n]; }
}

// ---------------------------------------------------------------------------
// Pass B: combine across chunks. One thread per (b,d,n) = 49152 threads.
// In-place: Pbuf[c] is overwritten with the ENTERING state of chunk c.
// ---------------------------------------------------------------------------
__global__ __launch_bounds__(256) void scan_passB_kernel(
    float* __restrict__ Pbuf, const float* __restrict__ Sbuf) {
    int idx = blockIdx.x * 256 + threadIdx.x;   // (b, d, n) flat
    int b = idx / (D_INNER * D_STATE);
    int dn = idx % (D_INNER * D_STATE);
    float H = 0.f;
    for (int c = 0; c < NCHUNK; c++) {
        size_t off = (((size_t)b * NCHUNK + c) * D_INNER * D_STATE) + dn;
        float p = Pbuf[off];
        float s = Sbuf[off];
        Pbuf[off] = H;          // entering state for chunk c
        H = p * H + s;
    }
}

// ---------------------------------------------------------------------------
// Pass C: recompute each chunk seeded with its entering state; emit gated y.
// ---------------------------------------------------------------------------
__global__ __launch_bounds__(256) void scan_passC_kernel(
    const float* __restrict__ xconv, const float* __restrict__ dt,
    const float* __restrict__ xdbl, const float* __restrict__ A_log,
    const float* __restrict__ Dv, const float* __restrict__ xz,
    const float* __restrict__ Hin,   // = Pbuf after pass B
    float* __restrict__ y) {
    int d = blockIdx.x * 256 + threadIdx.x;
    int c = blockIdx.y;
    int b = blockIdx.z;
    int t0 = c * CT;

    __shared__ float BCsh[CT][2 * D_STATE];
#pragma unroll
    for (int i = 0; i < 2; i++) {
        int idx = threadIdx.x + i * 256;       // 512 = CT * 32
        int row = idx >> 5, col = idx & 31;
        BCsh[row][col] = xdbl[((size_t)(b * L_SZ + t0 + row)) * XD + DT_RANK + col];
    }
    __syncthreads();

    float A[D_STATE];
#pragma unroll
    for (int n = 0; n < D_STATE; n++) A[n] = -expf(A_log[(size_t)d * D_STATE + n]);
    float Dd = Dv[d];

    float h[D_STATE];
    size_t hbase = (((size_t)b * NCHUNK + c) * D_INNER + d) * D_STATE;
#pragma unroll
    for (int n = 0; n < D_STATE; n++) h[n] = Hin[hbase + n];

    for (int t = 0; t < CT; t++) {
        size_t row = (size_t)b * L_SZ + t0 + t;
        float dtv = dt[row * D_INNER + d];
        float xv  = xconv[row * D_INNER + d];
        float acc = 0.f;
#pragma unroll
        for (int n = 0; n < D_STATE; n++) {
            float dA = expf(dtv * A[n]);
            h[n] = dA * h[n] + dtv * BCsh[t][n] * xv;
            acc += h[n] * BCsh[t][D_STATE + n];
        }
        acc += xv * Dd;
        float zv = xz[row * (2 * D_INNER) + D_INNER + d];
        y[row * D_INNER + d] = acc * siluf(zv);
    }
}

// ---------------------------------------------------------------------------
extern "C" void kernel_launch(void* const* d_in, const int* in_sizes, int n_in,
                              void* d_out, int out_size, void* d_ws, size_t ws_size,
                              hipStream_t stream) {
    const int*   input_ids    = (const int*)d_in[0];
    const int*   position_ids = (const int*)d_in[1];
    const float* emb_w        = (const float*)d_in[2];
    const float* pos_emb_w    = (const float*)d_in[3];
    const float* norm_w       = (const float*)d_in[4];
    const float* in_proj_w    = (const float*)d_in[5];
    const float* conv_w       = (const float*)d_in[6];
    const float* conv_b       = (const float*)d_in[7];
    const float* x_proj_w     = (const float*)d_in[8];
    const float* dt_proj_w    = (const float*)d_in[9];
    const float* dt_proj_b    = (const float*)d_in[10];
    const float* A_log        = (const float*)d_in[11];
    const float* D_vec        = (const float*)d_in[12];
    const float* out_proj_w   = (const float*)d_in[13];
    const float* norm_f_w     = (const float*)d_in[14];
    float* logits = (float*)d_out;

    // Workspace layout (floats). ~27M floats = ~108 MB.
    float* ws = (float*)d_ws;
    float* hidden   = ws; ws += (size_t)BL * D_MODEL;
    float* residual = ws; ws += (size_t)BL * D_MODEL;
    float* hs       = ws; ws += (size_t)BL * D_MODEL;
    float* xz       = ws; ws += (size_t)BL * 2 * D_INNER;
    float* xconv    = ws; ws += (size_t)BL * D_INNER;
    float* xdbl     = ws; ws += (size_t)BL * XD;
    float* dtbuf    = ws; ws += (size_t)BL * D_INNER;
    float* ybuf     = ws; ws += (size_t)BL * D_INNER;
    float* Pbuf     = ws; ws += (size_t)B_SZ * NCHUNK * D_INNER * D_STATE;
    float* Sbuf     = ws; ws += (size_t)B_SZ * NCHUNK * D_INNER * D_STATE;

    embed_kernel<<<(BL * D_MODEL + 255) / 256, 256, 0, stream>>>(
        input_ids, position_ids, emb_w, pos_emb_w, hidden, residual);

    for (int l = 0; l < N_LAYER; l++) {
        const float* nw  = norm_w     + (size_t)l * D_MODEL;
        const float* iw  = in_proj_w  + (size_t)l * 2 * D_INNER * D_MODEL;
        const float* cw  = conv_w     + (size_t)l * D_INNER * D_CONV;
        const float* cb  = conv_b     + (size_t)l * D_INNER;
        const float* xpw = x_proj_w   + (size_t)l * XD * D_INNER;
        const float* dtw = dt_proj_w  + (size_t)l * D_INNER * DT_RANK;
        const float* dtb = dt_proj_b  + (size_t)l * D_INNER;
        const float* al  = A_log      + (size_t)l * D_INNER * D_STATE;
        const float* dv  = D_vec      + (size_t)l * D_INNER;
        const float* ow  = out_proj_w + (size_t)l * D_MODEL * D_INNER;

        add_rmsnorm_kernel<<<BL, 256, 0, stream>>>(hidden, residual, nw, hs);

        {   // xz = hs @ in_w^T : M=2048, N=3072, K=768
            dim3 grid((2 * D_INNER) / BNT, BL / BMT);
            gemm_mfma_kernel<<<grid, 256, 0, stream>>>(hs, D_MODEL, iw, nullptr, xz,
                                                       BL, 2 * D_INNER, D_MODEL, 0);
        }

        conv_silu_kernel<<<(BL * D_INNER + 255) / 256, 256, 0, stream>>>(xz, cw, cb, xconv);

        {   // xdbl = xconv @ xp_w^T : M=2048, N=80, K=1536
            dim3 grid((XD + BNT - 1) / BNT, BL / BMT);
            gemm_mfma_kernel<<<grid, 256, 0, stream>>>(xconv, D_INNER, xpw, nullptr, xdbl,
                                                       BL, XD, D_INNER, 0);
        }

        {   // dt = softplus(xdbl[:, :48] @ dtw^T + dtb) : M=2048, N=1536, K=48
            // K=48 (%64 != 0) is safe: lda=80 keeps A over-reads in-row; B k-tail zeroed.
            dim3 grid(D_INNER / BNT, BL / BMT);
            gemm_mfma_kernel<<<grid, 256, 0, stream>>>(xdbl, XD, dtw, dtb,
                                                       dtbuf, BL, D_INNER, DT_RANK, 1);
        }

        {   // chunked selective scan
            dim3 gA(D_INNER / 256, NCHUNK, B_SZ);
            scan_passA_kernel<<<gA, 256, 0, stream>>>(xconv, dtbuf, xdbl, al, Pbuf, Sbuf);
            scan_passB_kernel<<<(B_SZ * D_INNER * D_STATE) / 256, 256, 0, stream>>>(Pbuf, Sbuf);
            scan_passC_kernel<<<gA, 256, 0, stream>>>(xconv, dtbuf, xdbl, al, dv, xz,
                                                      Pbuf, ybuf);
        }

        {   // hidden = y @ ow^T : M=2048, N=768, K=1536
            dim3 grid(D_MODEL / BNT, BL / BMT);
            gemm_mfma_kernel<<<grid, 256, 0, stream>>>(ybuf, D_INNER, ow, nullptr, hidden,
                                                       BL, D_MODEL, D_INNER, 0);
        }
    }

    add_rmsnorm_kernel<<<BL, 256, 0, stream>>>(hidden, residual, norm_f_w, hs);

    {   // logits = hs[:, :384] @ emb_w^T : M=2048, N=32000, K=384
        dim3 grid(VOCAB / BNT, BL / BMT);
        gemm_mfma_kernel<<<grid, 256, 0, stream>>>(hs, D_MODEL, emb_w, nullptr, logits,
                                                   BL, VOCAB, D_EMB, 0);
    }
}

// Round 2
// 1904.133 us; speedup vs baseline: 3.0697x; 1.3343x over previous
//
#include <hip/hip_runtime.h>
#include <math.h>

// Problem dims (compile-time)
#define B_SZ 2
#define L_SZ 1024
#define BL (B_SZ * L_SZ)          // 2048 tokens
#define D_MODEL 768
#define N_LAYER 6
#define VOCAB 32000
#define D_INNER 1536
#define D_STATE 16
#define D_CONV 4
#define DT_RANK 48
#define D_EMB 384
#define EPS 1e-5f

// Chunked-scan params: L = NCHUNK * CT
#define NCHUNK 64
#define CT 16
#define XD (DT_RANK + 2 * D_STATE)   // 80, xdbl row stride

typedef float vfloat4 __attribute__((ext_vector_type(4)));
typedef float f32x4  __attribute__((ext_vector_type(4)));
typedef short bf16x8 __attribute__((ext_vector_type(8)));

__device__ __forceinline__ float siluf(float x) {
    return x / (1.f + __expf(-x));
}

// ---------------------------------------------------------------------------
// Embedding
// ---------------------------------------------------------------------------
__global__ void embed_kernel(const int* __restrict__ ids, const int* __restrict__ pos,
                             const float* __restrict__ emb, const float* __restrict__ pemb,
                             float* __restrict__ hidden, float* __restrict__ residual) {
    int idx = blockIdx.x * blockDim.x + threadIdx.x;
    if (idx >= BL * D_MODEL) return;
    int c = idx % D_MODEL;
    int t = idx / D_MODEL;
    float v;
    if (c < D_EMB) v = emb[(size_t)ids[t] * D_EMB + c];
    else           v = pemb[(size_t)pos[t] * (D_MODEL - D_EMB) + (c - D_EMB)];
    hidden[idx] = v;
    residual[idx] = 0.f;
}

// ---------------------------------------------------------------------------
// residual += hidden; out = rmsnorm(residual) * w
// ---------------------------------------------------------------------------
__global__ __launch_bounds__(256) void add_rmsnorm_kernel(
    const float* __restrict__ hidden, float* __restrict__ residual,
    const float* __restrict__ w, float* __restrict__ out) {
    int row = blockIdx.x;
    const float* h = hidden + (size_t)row * D_MODEL;
    float* r = residual + (size_t)row * D_MODEL;
    float* o = out + (size_t)row * D_MODEL;

    float v[3];
    float ss = 0.f;
#pragma unroll
    for (int i = 0; i < 3; i++) {
        int c = threadIdx.x + i * 256;
        float x = h[c] + r[c];
        v[i] = x;
        r[c] = x;
        ss += x * x;
    }
#pragma unroll
    for (int off = 32; off > 0; off >>= 1) ss += __shfl_down(ss, off, 64);
    __shared__ float parts[4];
    __shared__ float s_scale;
    int wid = threadIdx.x >> 6;
    int lane = threadIdx.x & 63;
    if (lane == 0) parts[wid] = ss;
    __syncthreads();
    if (threadIdx.x == 0) {
        float tot = parts[0] + parts[1] + parts[2] + parts[3];
        s_scale = rsqrtf(tot / (float)D_MODEL + EPS);
    }
    __syncthreads();
    float scale = s_scale;
#pragma unroll
    for (int i = 0; i < 3; i++) {
        int c = threadIdx.x + i * 256;
        o[c] = v[i] * scale * w[c];
    }
}

// ---------------------------------------------------------------------------
// frag_convert: fp32 [R][ld] (logical K = Ksrc cols) -> split-bf16 hi/lo in
// fragment-tiled layout: tile = 128 rows x 64 k, within tile
//   offset = (sub*64 + lane)*8, sub = msub*2+ksub,
//   lane l holds elems [row = msub*16 + (l&15)][k = ksub*32 + (l>>4)*8 + j].
// This is EXACTLY the LDS layout the MFMA fragment reads expect, so the GEMM
// can stage tiles with linear global_load_lds. Zero-pads rows>=R, k>=Ksrc.
// One block per tile; both global sides coalesced; LDS (padded) does the
// transpose.
// ---------------------------------------------------------------------------
__global__ __launch_bounds__(256) void frag_convert_kernel(
    const float* __restrict__ src, int R, int ld, int Ksrc, int Kt,
    short* __restrict__ dh, short* __restrict__ dl) {
    int tile = blockIdx.x;
    int kt = tile % Kt, rt = tile / Kt;
    __shared__ float fs[128][65];
    int t = threadIdx.x;
    int rr = t >> 4;            // 0..15
    int c4 = (t & 15) * 4;      // 0..60
#pragma unroll
    for (int i = 0; i < 8; i++) {
        int rloc = rr + i * 16;
        int grow = rt * 128 + rloc;
        int gk = kt * 64 + c4;
        vfloat4 v = {0.f, 0.f, 0.f, 0.f};
        if (grow < R && gk < Ksrc)   // Ksrc % 4 == 0 always here
            v = *(const vfloat4*)&src[(size_t)grow * ld + gk];
        fs[rloc][c4 + 0] = v[0];
        fs[rloc][c4 + 1] = v[1];
        fs[rloc][c4 + 2] = v[2];
        fs[rloc][c4 + 3] = v[3];
    }
    __syncthreads();
#pragma unroll
    for (int i = 0; i < 4; i++) {
        int o = t + i * 256;          // 0..1023 = (sub, lane)
        int sub = o >> 6, ln = o & 63;
        int r = (sub >> 1) * 16 + (ln & 15);
        int k = (sub & 1) * 32 + (ln >> 4) * 8;
        bf16x8 h, l;
#pragma unroll
        for (int j = 0; j < 8; j++) {
            float x = fs[r][k + j];
            unsigned u = __float_as_uint(x);
            h[j] = (short)(u >> 16);                        // trunc bf16 hi
            float res = x - __uint_as_float(u & 0xffff0000u);
            l[j] = (short)(__float_as_uint(res) >> 16);     // trunc bf16 lo
        }
        size_t doff = (size_t)tile * 8192 + (size_t)o * 8;
        *(bf16x8*)&dh[doff] = h;
        *(bf16x8*)&dl[doff] = l;
    }
}

// ---------------------------------------------------------------------------
// Split-bf16 MFMA GEMM on pre-converted fragment-tiled operands.
// C[M=Mt*128][N] = A @ B^T via Ah*Bh + Ah*Bl + Al*Bh (fp32 acc).
// m97 structure: global_load_lds width-16 into linear LDS, 2 barriers/k-step.
// Block swizzle: bijective XCD chunking (m204) + m-fastest decomposition so
// the 16 m-blocks of one n-column share one XCD's L2 (B fetched once/XCD).
// Optional split-K (ksplit>1): atomicAdd into pre-zeroed C, bias must be null.
// ---------------------------------------------------------------------------
__device__ __forceinline__ void gload16(const short* g, short* l) {
    __builtin_amdgcn_global_load_lds(
        (const __attribute__((address_space(1))) void*)g,
        (__attribute__((address_space(3))) void*)l, 16, 0, 0);
}

__global__ __launch_bounds__(256, 2) void gemm_frag_kernel(
    const short* __restrict__ Af_h, const short* __restrict__ Af_l,
    const short* __restrict__ Bf_h, const short* __restrict__ Bf_l,
    const float* __restrict__ bias, float* __restrict__ C,
    int Mt, int Nt, int Kt, int N, int act, int ksplit) {

    __shared__ __align__(16) short smem[32768];   // 64 KB: Ah,Al,Bh,Bl tiles

    const int tid  = threadIdx.x;
    const int lane = tid & 63;
    const int w    = tid >> 6;
    const int wm   = w >> 1, wn = w & 1;

    // bijective XCD swizzle + m-fastest
    int nb  = Mt * Nt;
    int bid = blockIdx.x;
    int q = nb >> 3, r = nb & 7;
    int xcd = bid & 7, lin = bid >> 3;
    int wg = (xcd < r) ? (xcd * (q + 1) + lin) : (r * (q + 1) + (xcd - r) * q + lin);
    int mt = wg % Mt;
    int nt = wg / Mt;

    const int ktn = Kt / ksplit;
    const int kt0 = blockIdx.y * ktn;

    const short* ga_h = Af_h + ((size_t)mt * Kt + kt0) * 8192;
    const short* ga_l = Af_l + ((size_t)mt * Kt + kt0) * 8192;
    const short* gb_h = Bf_h + ((size_t)nt * Kt + kt0) * 8192;
    const short* gb_l = Bf_l + ((size_t)nt * Kt + kt0) * 8192;

    f32x4 acc[4][4];
#pragma unroll
    for (int i = 0; i < 4; i++)
#pragma unroll
        for (int j = 0; j < 4; j++)
            acc[i][j] = (f32x4){0.f, 0.f, 0.f, 0.f};

    for (int kk = 0; kk < ktn; kk++) {
        __syncthreads();   // readers of previous tile done
        {
            const size_t tb = (size_t)kk * 8192;
#pragma unroll
            for (int i = 0; i < 4; i++) {
                const int o = w * 2048 + i * 512;     // wave-uniform lds offset
                const int go = o + lane * 8;          // per-lane global offset
                gload16(ga_h + tb + go, &smem[o]);
                gload16(ga_l + tb + go, &smem[8192  + o]);
                gload16(gb_h + tb + go, &smem[16384 + o]);
                gload16(gb_l + tb + go, &smem[24576 + o]);
            }
        }
        __syncthreads();   // vmcnt(0) drained by compiler before barrier

#pragma unroll
        for (int ksub = 0; ksub < 2; ksub++) {
            bf16x8 a_h[4], a_l[4], b_h[4], b_l[4];
#pragma unroll
            for (int mi = 0; mi < 4; mi++) {
                const int off = (((wm * 4 + mi) * 2 + ksub) * 64 + lane) * 8;
                a_h[mi] = *(const bf16x8*)&smem[off];
                a_l[mi] = *(const bf16x8*)&smem[8192 + off];
            }
#pragma unroll
            for (int ni = 0; ni < 4; ni++) {
                const int off = (((wn * 4 + ni) * 2 + ksub) * 64 + lane) * 8;
                b_h[ni] = *(const bf16x8*)&smem[16384 + off];
                b_l[ni] = *(const bf16x8*)&smem[24576 + off];
            }
#pragma unroll
            for (int mi = 0; mi < 4; mi++)
#pragma unroll
                for (int ni = 0; ni < 4; ni++) {
                    acc[mi][ni] = __builtin_amdgcn_mfma_f32_16x16x32_bf16(
                        a_h[mi], b_h[ni], acc[mi][ni], 0, 0, 0);
                    acc[mi][ni] = __builtin_amdgcn_mfma_f32_16x16x32_bf16(
                        a_h[mi], b_l[ni], acc[mi][ni], 0, 0, 0);
                    acc[mi][ni] = __builtin_amdgcn_mfma_f32_16x16x32_bf16(
                        a_l[mi], b_h[ni], acc[mi][ni], 0, 0, 0);
                }
        }
    }

    // epilogue: C/D frag mapping col = lane&15, row = (lane>>4)*4 + r
    const int row0 = mt * 128 + wm * 64 + ((lane >> 4) << 2);
    const int col0 = nt * 128 + wn * 64 + (lane & 15);
    if (ksplit > 1) {
#pragma unroll
        for (int ni = 0; ni < 4; ni++) {
            const int col = col0 + ni * 16;
            if (col < N) {
#pragma unroll
                for (int mi = 0; mi < 4; mi++)
#pragma unroll
                    for (int rr = 0; rr < 4; rr++)
                        atomicAdd(&C[(size_t)(row0 + mi * 16 + rr) * N + col],
                                  acc[mi][ni][rr]);
            }
        }
    } else {
#pragma unroll
        for (int ni = 0; ni < 4; ni++) {
            const int col = col0 + ni * 16;
            if (col < N) {
                const float bv = bias ? bias[col] : 0.f;
#pragma unroll
                for (int mi = 0; mi < 4; mi++) {
#pragma unroll
                    for (int rr = 0; rr < 4; rr++) {
                        const int row = row0 + mi * 16 + rr;
                        float v = acc[mi][ni][rr] + bv;
                        if (act == 1) v = (v > 20.f) ? v : log1pf(__expf(v));
                        C[(size_t)row * N + col] = v;
                    }
                }
            }
        }
    }
}

// ---------------------------------------------------------------------------
// Depthwise causal conv1d (k=4) + bias + SiLU.
// ---------------------------------------------------------------------------
__global__ void conv_silu_kernel(const float* __restrict__ xz,
                                 const float* __restrict__ cw,
                                 const float* __restrict__ cb,
                                 float* __restrict__ out) {
    int idx = blockIdx.x * blockDim.x + threadIdx.x;
    if (idx >= BL * D_INNER) return;
    int d = idx % D_INNER;
    int t = (idx / D_INNER) % L_SZ;
    int b = idx / (D_INNER * L_SZ);
    const float* xcol = xz + (size_t)b * L_SZ * (2 * D_INNER) + d;
    float s = cb[d];
#pragma unroll
    for (int j = 0; j < D_CONV; j++) {
        int li = t - (D_CONV - 1) + j;
        if (li >= 0) s += xcol[(size_t)li * (2 * D_INNER)] * cw[d * D_CONV + j];
    }
    out[idx] = siluf(s);
}

// ---------------------------------------------------------------------------
// Chunked selective scan, pass A.
// ---------------------------------------------------------------------------
__global__ __launch_bounds__(256) void scan_passA_kernel(
    const float* __restrict__ xconv, const float* __restrict__ dt,
    const float* __restrict__ xdbl, const float* __restrict__ A_log,
    float* __restrict__ Pbuf, float* __restrict__ Sbuf) {
    int d = blockIdx.x * 256 + threadIdx.x;
    int c = blockIdx.y;
    int b = blockIdx.z;
    int t0 = c * CT;

    __shared__ float Bsh[CT][D_STATE];
    {
        int row = threadIdx.x >> 4, n = threadIdx.x & 15;   // 256 = CT*D_STATE
        Bsh[row][n] = xdbl[((size_t)(b * L_SZ + t0 + row)) * XD + DT_RANK + n];
    }
    __syncthreads();

    float A[D_STATE];
#pragma unroll
    for (int n = 0; n < D_STATE; n++) A[n] = -__expf(A_log[(size_t)d * D_STATE + n]);

    float P[D_STATE], S[D_STATE];
#pragma unroll
    for (int n = 0; n < D_STATE; n++) { P[n] = 1.f; S[n] = 0.f; }

    for (int t = 0; t < CT; t++) {
        size_t row = (size_t)b * L_SZ + t0 + t;
        float dtv = dt[row * D_INNER + d];
        float xv  = xconv[row * D_INNER + d];
#pragma unroll
        for (int n = 0; n < D_STATE; n++) {
            float dA = __expf(dtv * A[n]);
            P[n] *= dA;
            S[n] = dA * S[n] + dtv * Bsh[t][n] * xv;
        }
    }
    size_t base = (((size_t)b * NCHUNK + c) * D_INNER + d) * D_STATE;
#pragma unroll
    for (int n = 0; n < D_STATE; n++) { Pbuf[base + n] = P[n]; Sbuf[base + n] = S[n]; }
}

// ---------------------------------------------------------------------------
// Pass B: combine across chunks. Writes entering state per chunk to Hbuf
// (separate buffer so loads are hoistable; unroll-8 pipelines the latency).
// ---------------------------------------------------------------------------
__global__ __launch_bounds__(256) void scan_passB_kernel(
    const float* __restrict__ Pbuf, const float* __restrict__ Sbuf,
    float* __restrict__ Hbuf) {
    int idx = blockIdx.x * 256 + threadIdx.x;   // (b, d, n) flat
    int b = idx / (D_INNER * D_STATE);
    int dn = idx % (D_INNER * D_STATE);
    const int stride = D_INNER * D_STATE;
    size_t base = (size_t)b * NCHUNK * stride + dn;
    float H = 0.f;
#pragma unroll 8
    for (int c = 0; c < NCHUNK; c++) {
        size_t off = base + (size_t)c * stride;
        float p = Pbuf[off];
        float s = Sbuf[off];
        Hbuf[off] = H;
        H = p * H + s;
    }
}

// ---------------------------------------------------------------------------
// Pass C: recompute each chunk seeded with its entering state; emit gated y.
// ---------------------------------------------------------------------------
__global__ __launch_bounds__(256) void scan_passC_kernel(
    const float* __restrict__ xconv, const float* __restrict__ dt,
    const float* __restrict__ xdbl, const float* __restrict__ A_log,
    const float* __restrict__ Dv, const float* __restrict__ xz,
    const float* __restrict__ Hin,
    float* __restrict__ y) {
    int d = blockIdx.x * 256 + threadIdx.x;
    int c = blockIdx.y;
    int b = blockIdx.z;
    int t0 = c * CT;

    __shared__ float BCsh[CT][2 * D_STATE];
#pragma unroll
    for (int i = 0; i < 2; i++) {
        int idx = threadIdx.x + i * 256;       // 512 = CT * 32
        int row = idx >> 5, col = idx & 31;
        BCsh[row][col] = xdbl[((size_t)(b * L_SZ + t0 + row)) * XD + DT_RANK + col];
    }
    __syncthreads();

    float A[D_STATE];
#pragma unroll
    for (int n = 0; n < D_STATE; n++) A[n] = -__expf(A_log[(size_t)d * D_STATE + n]);
    float Dd = Dv[d];

    float h[D_STATE];
    size_t hbase = (((size_t)b * NCHUNK + c) * D_INNER + d) * D_STATE;
#pragma unroll
    for (int n = 0; n < D_STATE; n++) h[n] = Hin[hbase + n];

    for (int t = 0; t < CT; t++) {
        size_t row = (size_t)b * L_SZ + t0 + t;
        float dtv = dt[row * D_INNER + d];
        float xv  = xconv[row * D_INNER + d];
        float acc = 0.f;
#pragma unroll
        for (int n = 0; n < D_STATE; n++) {
            float dA = __expf(dtv * A[n]);
            h[n] = dA * h[n] + dtv * BCsh[t][n] * xv;
            acc += h[n] * BCsh[t][D_STATE + n];
        }
        acc += xv * Dd;
        float zv = xz[row * (2 * D_INNER) + D_INNER + d];
        y[row * D_INNER + d] = acc * siluf(zv);
    }
}

// ---------------------------------------------------------------------------
extern "C" void kernel_launch(void* const* d_in, const int* in_sizes, int n_in,
                              void* d_out, int out_size, void* d_ws, size_t ws_size,
                              hipStream_t stream) {
    const int*   input_ids    = (const int*)d_in[0];
    const int*   position_ids = (const int*)d_in[1];
    const float* emb_w        = (const float*)d_in[2];
    const float* pos_emb_w    = (const float*)d_in[3];
    const float* norm_w       = (const float*)d_in[4];
    const float* in_proj_w    = (const float*)d_in[5];
    const float* conv_w       = (const float*)d_in[6];
    const float* conv_b       = (const float*)d_in[7];
    const float* x_proj_w     = (const float*)d_in[8];
    const float* dt_proj_w    = (const float*)d_in[9];
    const float* dt_proj_b    = (const float*)d_in[10];
    const float* A_log        = (const float*)d_in[11];
    const float* D_vec        = (const float*)d_in[12];
    const float* out_proj_w   = (const float*)d_in[13];
    const float* norm_f_w     = (const float*)d_in[14];
    float* logits = (float*)d_out;

    // ---- workspace layout: fp32 region (~117 MB) then bf16 frag region (~97 MB)
    float* ws = (float*)d_ws;
    float* hidden   = ws; ws += (size_t)BL * D_MODEL;
    float* residual = ws; ws += (size_t)BL * D_MODEL;
    float* hs       = ws; ws += (size_t)BL * D_MODEL;
    float* xz       = ws; ws += (size_t)BL * 2 * D_INNER;
    float* xconv    = ws; ws += (size_t)BL * D_INNER;
    float* xdbl     = ws; ws += (size_t)BL * XD;
    float* dtbuf    = ws; ws += (size_t)BL * D_INNER;
    float* ybuf     = ws; ws += (size_t)BL * D_INNER;
    float* Pbuf     = ws; ws += (size_t)B_SZ * NCHUNK * D_INNER * D_STATE;
    float* Sbuf     = ws; ws += (size_t)B_SZ * NCHUNK * D_INNER * D_STATE;
    float* Hbuf     = ws; ws += (size_t)B_SZ * NCHUNK * D_INNER * D_STATE;

    short* sp = (short*)ws;
    auto salloc = [&](size_t n) { short* p = sp; sp += n; return p; };
    // tiles: 128 rows x 64 k = 8192 elems each
    const int KT_DM  = D_MODEL / 64;     // 12
    const int KT_DI  = D_INNER / 64;     // 24
    const int KT_EMB = D_EMB / 64;       // 6
    short* embf_h = salloc((size_t)(VOCAB/128) * KT_EMB * 8192);
    short* embf_l = salloc((size_t)(VOCAB/128) * KT_EMB * 8192);
    short* iwf_h  = salloc((size_t)(2*D_INNER/128) * KT_DM * 8192);
    short* iwf_l  = salloc((size_t)(2*D_INNER/128) * KT_DM * 8192);
    short* xpf_h  = salloc((size_t)1 * KT_DI * 8192);
    short* xpf_l  = salloc((size_t)1 * KT_DI * 8192);
    short* dtwf_h = salloc((size_t)(D_INNER/128) * 1 * 8192);
    short* dtwf_l = salloc((size_t)(D_INNER/128) * 1 * 8192);
    short* owf_h  = salloc((size_t)(D_MODEL/128) * KT_DI * 8192);
    short* owf_l  = salloc((size_t)(D_MODEL/128) * KT_DI * 8192);
    short* hsf_h  = salloc((size_t)(BL/128) * KT_DM * 8192);
    short* hsf_l  = salloc((size_t)(BL/128) * KT_DM * 8192);
    short* xcf_h  = salloc((size_t)(BL/128) * KT_DI * 8192);
    short* xcf_l  = salloc((size_t)(BL/128) * KT_DI * 8192);
    short* x48f_h = salloc((size_t)(BL/128) * 1 * 8192);
    short* x48f_l = salloc((size_t)(BL/128) * 1 * 8192);
    short* yf_h   = salloc((size_t)(BL/128) * KT_DI * 8192);
    short* yf_l   = salloc((size_t)(BL/128) * KT_DI * 8192);

    auto conv_frag = [&](const float* src, int R, int ld, int Ksrc, int Rt, int Kt,
                         short* dh, short* dl) {
        frag_convert_kernel<<<Rt * Kt, 256, 0, stream>>>(src, R, ld, Ksrc, Kt, dh, dl);
    };
    auto gemm = [&](const short* Ah, const short* Al, const short* Bh, const short* Bl,
                    const float* bias, float* C, int Mt, int Nt, int Kt, int N,
                    int act, int ksplit) {
        dim3 grid(Mt * Nt, ksplit);
        gemm_frag_kernel<<<grid, 256, 0, stream>>>(Ah, Al, Bh, Bl, bias, C,
                                                   Mt, Nt, Kt, N, act, ksplit);
    };

    embed_kernel<<<(BL * D_MODEL + 255) / 256, 256, 0, stream>>>(
        input_ids, position_ids, emb_w, pos_emb_w, hidden, residual);

    // emb_w frag (for logits), once
    conv_frag(emb_w, VOCAB, D_EMB, D_EMB, VOCAB / 128, KT_EMB, embf_h, embf_l);

    for (int l = 0; l < N_LAYER; l++) {
        const float* nw  = norm_w     + (size_t)l * D_MODEL;
        const float* iw  = in_proj_w  + (size_t)l * 2 * D_INNER * D_MODEL;
        const float* cw  = conv_w     + (size_t)l * D_INNER * D_CONV;
        const float* cb  = conv_b     + (size_t)l * D_INNER;
        const float* xpw = x_proj_w   + (size_t)l * XD * D_INNER;
        const float* dtw = dt_proj_w  + (size_t)l * D_INNER * DT_RANK;
        const float* dtb = dt_proj_b  + (size_t)l * D_INNER;
        const float* al  = A_log      + (size_t)l * D_INNER * D_STATE;
        const float* dv  = D_vec      + (size_t)l * D_INNER;
        const float* ow  = out_proj_w + (size_t)l * D_MODEL * D_INNER;

        add_rmsnorm_kernel<<<BL, 256, 0, stream>>>(hidden, residual, nw, hs);
        conv_frag(hs, BL, D_MODEL, D_MODEL, BL / 128, KT_DM, hsf_h, hsf_l);
        conv_frag(iw, 2 * D_INNER, D_MODEL, D_MODEL, 2 * D_INNER / 128, KT_DM,
                  iwf_h, iwf_l);

        // xz = hs @ in_w^T : Mt=16, Nt=24, Kt=12
        gemm(hsf_h, hsf_l, iwf_h, iwf_l, nullptr, xz,
             BL / 128, 2 * D_INNER / 128, KT_DM, 2 * D_INNER, 0, 1);

        conv_silu_kernel<<<(BL * D_INNER + 255) / 256, 256, 0, stream>>>(xz, cw, cb, xconv);
        conv_frag(xconv, BL, D_INNER, D_INNER, BL / 128, KT_DI, xcf_h, xcf_l);
        conv_frag(xpw, XD, D_INNER, D_INNER, 1, KT_DI, xpf_h, xpf_l);

        // xdbl = xconv @ xp_w^T : Nt=1 -> split-K x8 (atomic into zeroed buf)
        hipMemsetAsync(xdbl, 0, (size_t)BL * XD * sizeof(float), stream);
        gemm(xcf_h, xcf_l, xpf_h, xpf_l, nullptr, xdbl,
             BL / 128, 1, KT_DI, XD, 0, 8);

        // dt = softplus(xdbl[:, :48] @ dtw^T + dtb) : Kt=1 (zero-padded K)
        conv_frag(xdbl, BL, XD, DT_RANK, BL / 128, 1, x48f_h, x48f_l);
        conv_frag(dtw, D_INNER, DT_RANK, DT_RANK, D_INNER / 128, 1, dtwf_h, dtwf_l);
        gemm(x48f_h, x48f_l, dtwf_h, dtwf_l, dtb, dtbuf,
             BL / 128, D_INNER / 128, 1, D_INNER, 1, 1);

        // chunked selective scan
        {
            dim3 gA(D_INNER / 256, NCHUNK, B_SZ);
            scan_passA_kernel<<<gA, 256, 0, stream>>>(xconv, dtbuf, xdbl, al, Pbuf, Sbuf);
            scan_passB_kernel<<<(B_SZ * D_INNER * D_STATE) / 256, 256, 0, stream>>>(
                Pbuf, Sbuf, Hbuf);
            scan_passC_kernel<<<gA, 256, 0, stream>>>(xconv, dtbuf, xdbl, al, dv, xz,
                                                      Hbuf, ybuf);
        }

        // hidden = y @ ow^T : Nt=6 -> split-K x2
        conv_frag(ybuf, BL, D_INNER, D_INNER, BL / 128, KT_DI, yf_h, yf_l);
        conv_frag(ow, D_MODEL, D_INNER, D_INNER, D_MODEL / 128, KT_DI, owf_h, owf_l);
        hipMemsetAsync(hidden, 0, (size_t)BL * D_MODEL * sizeof(float), stream);
        gemm(yf_h, yf_l, owf_h, owf_l, nullptr, hidden,
             BL / 128, D_MODEL / 128, KT_DI, D_MODEL, 0, 2);
    }

    add_rmsnorm_kernel<<<BL, 256, 0, stream>>>(hidden, residual, norm_f_w, hs);
    // hs[:, :384] frag (reuse hsf buffers, Kt=6)
    conv_frag(hs, BL, D_MODEL, D_EMB, BL / 128, KT_EMB, hsf_h, hsf_l);

    // logits = hs[:, :384] @ emb_w^T : Mt=16, Nt=250, Kt=6
    gemm(hsf_h, hsf_l, embf_h, embf_l, nullptr, logits,
         BL / 128, VOCAB / 128, KT_EMB, VOCAB, 0, 1);
}

// Round 3
// 1845.773 us; speedup vs baseline: 3.1668x; 1.0316x over previous
//
#include <hip/hip_runtime.h>
#include <math.h>

// Problem dims (compile-time)
#define B_SZ 2
#define L_SZ 1024
#define BL (B_SZ * L_SZ)          // 2048 tokens
#define D_MODEL 768
#define N_LAYER 6
#define VOCAB 32000
#define D_INNER 1536
#define D_STATE 16
#define D_CONV 4
#define DT_RANK 48
#define D_EMB 384
#define EPS 1e-5f

// Chunked-scan params: L = NCHUNK * CT
#define NCHUNK 64
#define CT 16
#define XD (DT_RANK + 2 * D_STATE)   // 80, xdbl row stride

typedef float vfloat4 __attribute__((ext_vector_type(4)));
typedef float f32x4  __attribute__((ext_vector_type(4)));
typedef short bf16x8 __attribute__((ext_vector_type(8)));

__device__ __forceinline__ float siluf(float x) {
    return x / (1.f + __expf(-x));
}

// ---------------------------------------------------------------------------
// Embedding
// ---------------------------------------------------------------------------
__global__ void embed_kernel(const int* __restrict__ ids, const int* __restrict__ pos,
                             const float* __restrict__ emb, const float* __restrict__ pemb,
                             float* __restrict__ hidden, float* __restrict__ residual) {
    int idx = blockIdx.x * blockDim.x + threadIdx.x;
    if (idx >= BL * D_MODEL) return;
    int c = idx % D_MODEL;
    int t = idx / D_MODEL;
    float v;
    if (c < D_EMB) v = emb[(size_t)ids[t] * D_EMB + c];
    else           v = pemb[(size_t)pos[t] * (D_MODEL - D_EMB) + (c - D_EMB)];
    hidden[idx] = v;
    residual[idx] = 0.f;
}

// ---------------------------------------------------------------------------
// residual += hidden; out = rmsnorm(residual) * w
// ---------------------------------------------------------------------------
__global__ __launch_bounds__(256) void add_rmsnorm_kernel(
    const float* __restrict__ hidden, float* __restrict__ residual,
    const float* __restrict__ w, float* __restrict__ out) {
    int row = blockIdx.x;
    const float* h = hidden + (size_t)row * D_MODEL;
    float* r = residual + (size_t)row * D_MODEL;
    float* o = out + (size_t)row * D_MODEL;

    float v[3];
    float ss = 0.f;
#pragma unroll
    for (int i = 0; i < 3; i++) {
        int c = threadIdx.x + i * 256;
        float x = h[c] + r[c];
        v[i] = x;
        r[c] = x;
        ss += x * x;
    }
#pragma unroll
    for (int off = 32; off > 0; off >>= 1) ss += __shfl_down(ss, off, 64);
    __shared__ float parts[4];
    __shared__ float s_scale;
    int wid = threadIdx.x >> 6;
    int lane = threadIdx.x & 63;
    if (lane == 0) parts[wid] = ss;
    __syncthreads();
    if (threadIdx.x == 0) {
        float tot = parts[0] + parts[1] + parts[2] + parts[3];
        s_scale = rsqrtf(tot / (float)D_MODEL + EPS);
    }
    __syncthreads();
    float scale = s_scale;
#pragma unroll
    for (int i = 0; i < 3; i++) {
        int c = threadIdx.x + i * 256;
        o[c] = v[i] * scale * w[c];
    }
}

// ---------------------------------------------------------------------------
// frag_convert: fp32 [R][ld] (logical K = Ksrc cols) -> split-bf16 hi/lo in
// fragment-tiled layout. Tile = 128 rows x 32 k = 4096 elems; within tile
// lane l at (msub*64+l)*8 holds [row = msub*16 + (l&15)][k = (l>>4)*8 + j].
// Tiles laid out row-tile-major: (rt * K32 + kt32) * 4096.
// One block covers 128 rows x 64 k (two 32-k tiles). Zero-pads rows>=R,
// k>=Ksrc. Optional layer batching via blockIdx.y with elem strides.
// ---------------------------------------------------------------------------
__global__ __launch_bounds__(256) void frag_convert_kernel(
    const float* __restrict__ src, int R, int ld, int Ksrc, int Kt64,
    size_t src_lstride, size_t dst_lstride,
    short* __restrict__ dh, short* __restrict__ dl) {
    int tile = blockIdx.x;
    int lyr = blockIdx.y;
    const float* s = src + (size_t)lyr * src_lstride;
    short* dhp = dh + (size_t)lyr * dst_lstride;
    short* dlp = dl + (size_t)lyr * dst_lstride;
    int kt = tile % Kt64, rt = tile / Kt64;
    const int K32 = Kt64 * 2;

    __shared__ float fs[128][65];
    int t = threadIdx.x;
    int rr = t >> 4;            // 0..15
    int c4 = (t & 15) * 4;      // 0..60
#pragma unroll
    for (int i = 0; i < 8; i++) {
        int rloc = rr + i * 16;
        int grow = rt * 128 + rloc;
        int gk = kt * 64 + c4;
        vfloat4 v = {0.f, 0.f, 0.f, 0.f};
        if (grow < R && gk < Ksrc)   // Ksrc % 4 == 0 always here
            v = *(const vfloat4*)&s[(size_t)grow * ld + gk];
        fs[rloc][c4 + 0] = v[0];
        fs[rloc][c4 + 1] = v[1];
        fs[rloc][c4 + 2] = v[2];
        fs[rloc][c4 + 3] = v[3];
    }
    __syncthreads();
#pragma unroll
    for (int i = 0; i < 4; i++) {
        int o = t + i * 256;          // 0..1023
        int sub = o >> 6, ln = o & 63;
        int msub = sub >> 1, ksub = sub & 1;
        int r = msub * 16 + (ln & 15);
        int k = ksub * 32 + (ln >> 4) * 8;
        bf16x8 h, l;
#pragma unroll
        for (int j = 0; j < 8; j++) {
            float x = fs[r][k + j];
            unsigned u = __float_as_uint(x);
            h[j] = (short)(u >> 16);                        // trunc bf16 hi
            float res = x - __uint_as_float(u & 0xffff0000u);
            l[j] = (short)(__float_as_uint(res) >> 16);     // trunc bf16 lo
        }
        size_t doff = ((size_t)rt * K32 + kt * 2 + ksub) * 4096
                    + (size_t)(msub * 64 + ln) * 8;
        *(bf16x8*)&dhp[doff] = h;
        *(bf16x8*)&dlp[doff] = l;
    }
}

// ---------------------------------------------------------------------------
// Split-bf16 MFMA GEMM on pre-converted fragment-tiled operands.
// BK=32: 4 operand tiles (Ah|Al|Bh|Bl) x 8KB = 32KB LDS -> 4 blocks/CU
// (m132 lesson: 64KB/2-block was the occupancy cliff; the vmcnt(0)+barrier
// drain of the 1-phase structure is hidden by the other resident blocks).
// Bijective XCD swizzle + m-fastest decomposition for B-panel L2 locality.
// Optional split-K (ksplit>1): atomicAdd into pre-zeroed C, bias must be null.
// ---------------------------------------------------------------------------
__device__ __forceinline__ void gload16(const short* g, short* l) {
    __builtin_amdgcn_global_load_lds(
        (const __attribute__((address_space(1))) void*)g,
        (__attribute__((address_space(3))) void*)l, 16, 0, 0);
}

__global__ __launch_bounds__(256, 4) void gemm_frag_kernel(
    const short* __restrict__ Af_h, const short* __restrict__ Af_l,
    const short* __restrict__ Bf_h, const short* __restrict__ Bf_l,
    const float* __restrict__ bias, float* __restrict__ C,
    int Mt, int Nt, int K32, int N, int act, int ksplit) {

    __shared__ __align__(16) short smem[16384];   // 32 KB

    const int tid  = threadIdx.x;
    const int lane = tid & 63;
    const int w    = tid >> 6;
    const int wm   = w >> 1, wn = w & 1;

    // bijective XCD swizzle + m-fastest
    int nb  = Mt * Nt;
    int bid = blockIdx.x;
    int q = nb >> 3, r = nb & 7;
    int xcd = bid & 7, lin = bid >> 3;
    int wg = (xcd < r) ? (xcd * (q + 1) + lin) : (r * (q + 1) + (xcd - r) * q + lin);
    int mt = wg % Mt;
    int nt = wg / Mt;

    const int ktn = K32 / ksplit;
    const int kt0 = blockIdx.y * ktn;

    const short* ga_h = Af_h + ((size_t)mt * K32 + kt0) * 4096;
    const short* ga_l = Af_l + ((size_t)mt * K32 + kt0) * 4096;
    const short* gb_h = Bf_h + ((size_t)nt * K32 + kt0) * 4096;
    const short* gb_l = Bf_l + ((size_t)nt * K32 + kt0) * 4096;

    f32x4 acc[4][4];
#pragma unroll
    for (int i = 0; i < 4; i++)
#pragma unroll
        for (int j = 0; j < 4; j++)
            acc[i][j] = (f32x4){0.f, 0.f, 0.f, 0.f};

    for (int kk = 0; kk < ktn; kk++) {
        __syncthreads();   // readers of previous tile done
        {
            const size_t tb = (size_t)kk * 4096;
#pragma unroll
            for (int i = 0; i < 2; i++) {
                const int o = w * 1024 + i * 512;     // wave-uniform lds offset
                const int go = o + lane * 8;          // per-lane global offset
                gload16(ga_h + tb + go, &smem[o]);
                gload16(ga_l + tb + go, &smem[4096  + o]);
                gload16(gb_h + tb + go, &smem[8192  + o]);
                gload16(gb_l + tb + go, &smem[12288 + o]);
            }
        }
        __syncthreads();   // vmcnt(0) drained by compiler before barrier

        bf16x8 a_h[4], a_l[4], b_h[4], b_l[4];
#pragma unroll
        for (int mi = 0; mi < 4; mi++) {
            const int off = ((wm * 4 + mi) * 64 + lane) * 8;
            a_h[mi] = *(const bf16x8*)&smem[off];
            a_l[mi] = *(const bf16x8*)&smem[4096 + off];
        }
#pragma unroll
        for (int ni = 0; ni < 4; ni++) {
            const int off = ((wn * 4 + ni) * 64 + lane) * 8;
            b_h[ni] = *(const bf16x8*)&smem[8192 + off];
            b_l[ni] = *(const bf16x8*)&smem[12288 + off];
        }
#pragma unroll
        for (int mi = 0; mi < 4; mi++)
#pragma unroll
            for (int ni = 0; ni < 4; ni++) {
                acc[mi][ni] = __builtin_amdgcn_mfma_f32_16x16x32_bf16(
                    a_h[mi], b_h[ni], acc[mi][ni], 0, 0, 0);
                acc[mi][ni] = __builtin_amdgcn_mfma_f32_16x16x32_bf16(
                    a_h[mi], b_l[ni], acc[mi][ni], 0, 0, 0);
                acc[mi][ni] = __builtin_amdgcn_mfma_f32_16x16x32_bf16(
                    a_l[mi], b_h[ni], acc[mi][ni], 0, 0, 0);
            }
    }

    // epilogue: C/D frag mapping col = lane&15, row = (lane>>4)*4 + r
    const int row0 = mt * 128 + wm * 64 + ((lane >> 4) << 2);
    const int col0 = nt * 128 + wn * 64 + (lane & 15);
    if (ksplit > 1) {
#pragma unroll
        for (int ni = 0; ni < 4; ni++) {
            const int col = col0 + ni * 16;
            if (col < N) {
#pragma unroll
                for (int mi = 0; mi < 4; mi++)
#pragma unroll
                    for (int rr = 0; rr < 4; rr++)
                        atomicAdd(&C[(size_t)(row0 + mi * 16 + rr) * N + col],
                                  acc[mi][ni][rr]);
            }
        }
    } else {
#pragma unroll
        for (int ni = 0; ni < 4; ni++) {
            const int col = col0 + ni * 16;
            if (col < N) {
                const float bv = bias ? bias[col] : 0.f;
#pragma unroll
                for (int mi = 0; mi < 4; mi++) {
#pragma unroll
                    for (int rr = 0; rr < 4; rr++) {
                        const int row = row0 + mi * 16 + rr;
                        float v = acc[mi][ni][rr] + bv;
                        if (act == 1) v = (v > 20.f) ? v : log1pf(__expf(v));
                        C[(size_t)row * N + col] = v;
                    }
                }
            }
        }
    }
}

// ---------------------------------------------------------------------------
// Depthwise causal conv1d (k=4) + bias + SiLU. Also zeroes xdbl (fused
// memset; xdbl is atomically accumulated by the next GEMM).
// ---------------------------------------------------------------------------
__global__ void conv_silu_kernel(const float* __restrict__ xz,
                                 const float* __restrict__ cw,
                                 const float* __restrict__ cb,
                                 float* __restrict__ out,
                                 float* __restrict__ xdbl_zero) {
    int idx = blockIdx.x * blockDim.x + threadIdx.x;
    if (idx >= BL * D_INNER) return;
    if (idx < BL * XD) xdbl_zero[idx] = 0.f;
    int d = idx % D_INNER;
    int t = (idx / D_INNER) % L_SZ;
    int b = idx / (D_INNER * L_SZ);
    const float* xcol = xz + (size_t)b * L_SZ * (2 * D_INNER) + d;
    float s = cb[d];
#pragma unroll
    for (int j = 0; j < D_CONV; j++) {
        int li = t - (D_CONV - 1) + j;
        if (li >= 0) s += xcol[(size_t)li * (2 * D_INNER)] * cw[d * D_CONV + j];
    }
    out[idx] = siluf(s);
}

// ---------------------------------------------------------------------------
// Chunked selective scan, pass A.
// ---------------------------------------------------------------------------
__global__ __launch_bounds__(256) void scan_passA_kernel(
    const float* __restrict__ xconv, const float* __restrict__ dt,
    const float* __restrict__ xdbl, const float* __restrict__ A_log,
    float* __restrict__ Pbuf, float* __restrict__ Sbuf) {
    int d = blockIdx.x * 256 + threadIdx.x;
    int c = blockIdx.y;
    int b = blockIdx.z;
    int t0 = c * CT;

    __shared__ float Bsh[CT][D_STATE];
    {
        int row = threadIdx.x >> 4, n = threadIdx.x & 15;   // 256 = CT*D_STATE
        Bsh[row][n] = xdbl[((size_t)(b * L_SZ + t0 + row)) * XD + DT_RANK + n];
    }
    __syncthreads();

    float A[D_STATE];
#pragma unroll
    for (int n = 0; n < D_STATE; n++) A[n] = -__expf(A_log[(size_t)d * D_STATE + n]);

    float P[D_STATE], S[D_STATE];
#pragma unroll
    for (int n = 0; n < D_STATE; n++) { P[n] = 1.f; S[n] = 0.f; }

    for (int t = 0; t < CT; t++) {
        size_t row = (size_t)b * L_SZ + t0 + t;
        float dtv = dt[row * D_INNER + d];
        float xv  = xconv[row * D_INNER + d];
#pragma unroll
        for (int n = 0; n < D_STATE; n++) {
            float dA = __expf(dtv * A[n]);
            P[n] *= dA;
            S[n] = dA * S[n] + dtv * Bsh[t][n] * xv;
        }
    }
    size_t base = (((size_t)b * NCHUNK + c) * D_INNER + d) * D_STATE;
#pragma unroll
    for (int n = 0; n < D_STATE; n++) { Pbuf[base + n] = P[n]; Sbuf[base + n] = S[n]; }
}

// ---------------------------------------------------------------------------
// Pass B: combine across chunks; entering state per chunk -> Hbuf.
// ---------------------------------------------------------------------------
__global__ __launch_bounds__(256) void scan_passB_kernel(
    const float* __restrict__ Pbuf, const float* __restrict__ Sbuf,
    float* __restrict__ Hbuf) {
    int idx = blockIdx.x * 256 + threadIdx.x;   // (b, d, n) flat
    int b = idx / (D_INNER * D_STATE);
    int dn = idx % (D_INNER * D_STATE);
    const int stride = D_INNER * D_STATE;
    size_t base = (size_t)b * NCHUNK * stride + dn;
    float H = 0.f;
#pragma unroll 8
    for (int c = 0; c < NCHUNK; c++) {
        size_t off = base + (size_t)c * stride;
        float p = Pbuf[off];
        float s = Sbuf[off];
        Hbuf[off] = H;
        H = p * H + s;
    }
}

// ---------------------------------------------------------------------------
// Pass C: recompute each chunk seeded with its entering state; emit gated y.
// ---------------------------------------------------------------------------
__global__ __launch_bounds__(256) void scan_passC_kernel(
    const float* __restrict__ xconv, const float* __restrict__ dt,
    const float* __restrict__ xdbl, const float* __restrict__ A_log,
    const float* __restrict__ Dv, const float* __restrict__ xz,
    const float* __restrict__ Hin,
    float* __restrict__ y) {
    int d = blockIdx.x * 256 + threadIdx.x;
    int c = blockIdx.y;
    int b = blockIdx.z;
    int t0 = c * CT;

    __shared__ float BCsh[CT][2 * D_STATE];
#pragma unroll
    for (int i = 0; i < 2; i++) {
        int idx = threadIdx.x + i * 256;       // 512 = CT * 32
        int row = idx >> 5, col = idx & 31;
        BCsh[row][col] = xdbl[((size_t)(b * L_SZ + t0 + row)) * XD + DT_RANK + col];
    }
    __syncthreads();

    float A[D_STATE];
#pragma unroll
    for (int n = 0; n < D_STATE; n++) A[n] = -__expf(A_log[(size_t)d * D_STATE + n]);
    float Dd = Dv[d];

    float h[D_STATE];
    size_t hbase = (((size_t)b * NCHUNK + c) * D_INNER + d) * D_STATE;
#pragma unroll
    for (int n = 0; n < D_STATE; n++) h[n] = Hin[hbase + n];

    for (int t = 0; t < CT; t++) {
        size_t row = (size_t)b * L_SZ + t0 + t;
        float dtv = dt[row * D_INNER + d];
        float xv  = xconv[row * D_INNER + d];
        float acc = 0.f;
#pragma unroll
        for (int n = 0; n < D_STATE; n++) {
            float dA = __expf(dtv * A[n]);
            h[n] = dA * h[n] + dtv * BCsh[t][n] * xv;
            acc += h[n] * BCsh[t][D_STATE + n];
        }
        acc += xv * Dd;
        float zv = xz[row * (2 * D_INNER) + D_INNER + d];
        y[row * D_INNER + d] = acc * siluf(zv);
    }
}

// ---------------------------------------------------------------------------
extern "C" void kernel_launch(void* const* d_in, const int* in_sizes, int n_in,
                              void* d_out, int out_size, void* d_ws, size_t ws_size,
                              hipStream_t stream) {
    const int*   input_ids    = (const int*)d_in[0];
    const int*   position_ids = (const int*)d_in[1];
    const float* emb_w        = (const float*)d_in[2];
    const float* pos_emb_w    = (const float*)d_in[3];
    const float* norm_w       = (const float*)d_in[4];
    const float* in_proj_w    = (const float*)d_in[5];
    const float* conv_w       = (const float*)d_in[6];
    const float* conv_b       = (const float*)d_in[7];
    const float* x_proj_w     = (const float*)d_in[8];
    const float* dt_proj_w    = (const float*)d_in[9];
    const float* dt_proj_b    = (const float*)d_in[10];
    const float* A_log        = (const float*)d_in[11];
    const float* D_vec        = (const float*)d_in[12];
    const float* out_proj_w   = (const float*)d_in[13];
    const float* norm_f_w     = (const float*)d_in[14];
    float* logits = (float*)d_out;

    // ---- workspace: fp32 region (~122 MB) then bf16 frag region (~100 MB)
    float* ws = (float*)d_ws;
    float* hidden   = ws; ws += (size_t)BL * D_MODEL;
    float* residual = ws; ws += (size_t)BL * D_MODEL;
    float* hs       = ws; ws += (size_t)BL * D_MODEL;
    float* xz       = ws; ws += (size_t)BL * 2 * D_INNER;
    float* xconv    = ws; ws += (size_t)BL * D_INNER;
    float* xdbl     = ws; ws += (size_t)BL * XD;
    float* dtbuf    = ws; ws += (size_t)BL * D_INNER;
    float* ybuf     = ws; ws += (size_t)BL * D_INNER;
    float* Pbuf     = ws; ws += (size_t)B_SZ * NCHUNK * D_INNER * D_STATE;
    float* Sbuf     = ws; ws += (size_t)B_SZ * NCHUNK * D_INNER * D_STATE;
    float* Hbuf     = ws; ws += (size_t)B_SZ * NCHUNK * D_INNER * D_STATE;

    short* sp = (short*)ws;
    auto salloc = [&](size_t n) { short* p = sp; sp += n; return p; };
    // K32 counts (32-wide k-tiles), tile = 4096 shorts
    const int K32_DM  = D_MODEL / 32;    // 24
    const int K32_DI  = D_INNER / 32;    // 48
    const int K32_EMB = D_EMB / 32;      // 12
    const size_t XPF_L  = (size_t)1 * K32_DI * 4096;                 // per-layer
    const size_t DTWF_L = (size_t)(D_INNER / 128) * 2 * 4096;        // per-layer
    short* embf_h = salloc((size_t)(VOCAB/128) * K32_EMB * 4096);
    short* embf_l = salloc((size_t)(VOCAB/128) * K32_EMB * 4096);
    short* iwf_h  = salloc((size_t)(2*D_INNER/128) * K32_DM * 4096);
    short* iwf_l  = salloc((size_t)(2*D_INNER/128) * K32_DM * 4096);
    short* xpf_h  = salloc(XPF_L * N_LAYER);
    short* xpf_l  = salloc(XPF_L * N_LAYER);
    short* dtwf_h = salloc(DTWF_L * N_LAYER);
    short* dtwf_l = salloc(DTWF_L * N_LAYER);
    short* owf_h  = salloc((size_t)(D_MODEL/128) * K32_DI * 4096);
    short* owf_l  = salloc((size_t)(D_MODEL/128) * K32_DI * 4096);
    short* hsf_h  = salloc((size_t)(BL/128) * K32_DM * 4096);
    short* hsf_l  = salloc((size_t)(BL/128) * K32_DM * 4096);
    short* xcf_h  = salloc((size_t)(BL/128) * K32_DI * 4096);
    short* xcf_l  = salloc((size_t)(BL/128) * K32_DI * 4096);
    short* x48f_h = salloc((size_t)(BL/128) * 2 * 4096);
    short* x48f_l = salloc((size_t)(BL/128) * 2 * 4096);
    short* yf_h   = salloc((size_t)(BL/128) * K32_DI * 4096);
    short* yf_l   = salloc((size_t)(BL/128) * K32_DI * 4096);

    auto conv_frag = [&](const float* src, int R, int ld, int Ksrc, int Rt, int Kt64,
                         short* dh, short* dl, int layers = 1,
                         size_t sstr = 0, size_t dstr = 0) {
        dim3 grid(Rt * Kt64, layers);
        frag_convert_kernel<<<grid, 256, 0, stream>>>(src, R, ld, Ksrc, Kt64,
                                                      sstr, dstr, dh, dl);
    };
    auto gemm = [&](const short* Ah, const short* Al, const short* Bh, const short* Bl,
                    const float* bias, float* C, int Mt, int Nt, int K32, int N,
                    int act, int ksplit) {
        dim3 grid(Mt * Nt, ksplit);
        gemm_frag_kernel<<<grid, 256, 0, stream>>>(Ah, Al, Bh, Bl, bias, C,
                                                   Mt, Nt, K32, N, act, ksplit);
    };

    embed_kernel<<<(BL * D_MODEL + 255) / 256, 256, 0, stream>>>(
        input_ids, position_ids, emb_w, pos_emb_w, hidden, residual);

    // one-time weight conversions: emb (logits B), xpw + dtw batched over layers
    conv_frag(emb_w, VOCAB, D_EMB, D_EMB, VOCAB / 128, D_EMB / 64, embf_h, embf_l);
    conv_frag(x_proj_w, XD, D_INNER, D_INNER, 1, D_INNER / 64, xpf_h, xpf_l,
              N_LAYER, (size_t)XD * D_INNER, XPF_L);
    conv_frag(dt_proj_w, D_INNER, DT_RANK, DT_RANK, D_INNER / 128, 1, dtwf_h, dtwf_l,
              N_LAYER, (size_t)D_INNER * DT_RANK, DTWF_L);

    for (int l = 0; l < N_LAYER; l++) {
        const float* nw  = norm_w     + (size_t)l * D_MODEL;
        const float* iw  = in_proj_w  + (size_t)l * 2 * D_INNER * D_MODEL;
        const float* cw  = conv_w     + (size_t)l * D_INNER * D_CONV;
        const float* cb  = conv_b     + (size_t)l * D_INNER;
        const float* dtb = dt_proj_b  + (size_t)l * D_INNER;
        const float* al  = A_log      + (size_t)l * D_INNER * D_STATE;
        const float* dv  = D_vec      + (size_t)l * D_INNER;
        const float* ow  = out_proj_w + (size_t)l * D_MODEL * D_INNER;

        add_rmsnorm_kernel<<<BL, 256, 0, stream>>>(hidden, residual, nw, hs);
        conv_frag(hs, BL, D_MODEL, D_MODEL, BL / 128, D_MODEL / 64, hsf_h, hsf_l);
        conv_frag(iw, 2 * D_INNER, D_MODEL, D_MODEL, 2 * D_INNER / 128, D_MODEL / 64,
                  iwf_h, iwf_l);

        // xz = hs @ in_w^T : Mt=16, Nt=24, K32=24
        gemm(hsf_h, hsf_l, iwf_h, iwf_l, nullptr, xz,
             BL / 128, 2 * D_INNER / 128, K32_DM, 2 * D_INNER, 0, 1);

        conv_silu_kernel<<<(BL * D_INNER + 255) / 256, 256, 0, stream>>>(
            xz, cw, cb, xconv, xdbl);
        conv_frag(xconv, BL, D_INNER, D_INNER, BL / 128, D_INNER / 64, xcf_h, xcf_l);

        // xdbl = xconv @ xp_w^T : Nt=1 -> split-K x8 (atomic into zeroed buf)
        gemm(xcf_h, xcf_l, xpf_h + l * XPF_L, xpf_l + l * XPF_L, nullptr, xdbl,
             BL / 128, 1, K32_DI, XD, 0, 8);

        // dt = softplus(xdbl[:, :48] @ dtw^T + dtb) : K32=2 (zero-padded K)
        conv_frag(xdbl, BL, XD, DT_RANK, BL / 128, 1, x48f_h, x48f_l);
        gemm(x48f_h, x48f_l, dtwf_h + l * DTWF_L, dtwf_l + l * DTWF_L, dtb, dtbuf,
             BL / 128, D_INNER / 128, 2, D_INNER, 1, 1);

        // chunked selective scan
        {
            dim3 gA(D_INNER / 256, NCHUNK, B_SZ);
            scan_passA_kernel<<<gA, 256, 0, stream>>>(xconv, dtbuf, xdbl, al, Pbuf, Sbuf);
            scan_passB_kernel<<<(B_SZ * D_INNER * D_STATE) / 256, 256, 0, stream>>>(
                Pbuf, Sbuf, Hbuf);
            scan_passC_kernel<<<gA, 256, 0, stream>>>(xconv, dtbuf, xdbl, al, dv, xz,
                                                      Hbuf, ybuf);
        }

        // hidden = y @ ow^T : Nt=6 -> split-K x4 (384 blocks)
        conv_frag(ybuf, BL, D_INNER, D_INNER, BL / 128, D_INNER / 64, yf_h, yf_l);
        conv_frag(ow, D_MODEL, D_INNER, D_INNER, D_MODEL / 128, D_INNER / 64,
                  owf_h, owf_l);
        hipMemsetAsync(hidden, 0, (size_t)BL * D_MODEL * sizeof(float), stream);
        gemm(yf_h, yf_l, owf_h, owf_l, nullptr, hidden,
             BL / 128, D_MODEL / 128, K32_DI, D_MODEL, 0, 4);
    }

    add_rmsnorm_kernel<<<BL, 256, 0, stream>>>(hidden, residual, norm_f_w, hs);
    // hs[:, :384] frag (reuse hsf buffers, K32=12)
    conv_frag(hs, BL, D_MODEL, D_EMB, BL / 128, D_EMB / 64, hsf_h, hsf_l);

    // logits = hs[:, :384] @ emb_w^T : Mt=16, Nt=250, K32=12
    gemm(hsf_h, hsf_l, embf_h, embf_l, nullptr, logits,
         BL / 128, VOCAB / 128, K32_EMB, VOCAB, 0, 1);
}